// Round 3
// baseline (5453.396 us; speedup 1.0000x reference)
//
#include <hip/hip_runtime.h>

// LGA3D x3 (GANet local guided aggregation), fp32.
// Round 3: barrier-free wave-private tiles. Each 64-lane wave owns a 2h x 32w x 4c
// tile, stages its own halo plane (216 float4 cells) into wave-private LDS, and
// reads only its own writes -> no __syncthreads, no vmcnt(0) drains. Staging loads
// for plane p+1 are issued before computing plane p (software pipeline via 16
// prefetch VGPRs). Depth split x2 for 16 waves/CU.

namespace {
constexpr int C  = 16, D = 48, H = 128, W = 256;
constexpr int NC = 4;                 // channels per LDS cell (float4, ds_read_b128)
constexpr int TW = 32, TH = 2;        // per-wave output tile
constexpr int DS = 2;                 // depth split
constexpr int DT = D / DS;            // 24 output planes per block
constexpr int LH = TH + 4;            // 6 rows:  h0-2 .. h0+3
constexpr int LW = TW + 4;            // 36 cols: w0-2 .. w0+33
constexpr int CELLS = LH * LW;        // 216 cells per plane buffer
constexpr int HW = H * W;
constexpr int DHW = D * HW;
constexpr int NF = 75;
}

__global__ __launch_bounds__(64, 4)
void lga_pass(const float* __restrict__ in, const float* __restrict__ filt,
              float* __restrict__ out)
{
    __shared__ float4 buf[2][CELLS];  // 6912 B, wave-private (block = 1 wave)

    const int lane = threadIdx.x;     // 0..63
    const int hl = lane >> 5;         // 0..1
    const int wl = lane & 31;         // 0..31
    const int w0 = blockIdx.x * TW;
    const int h0 = blockIdx.y * TH;
    const int zz = blockIdx.z;
    const int c0  = (zz >> 1) * NC;
    const int dlo = (zz & 1) * DT;

    const int h = h0 + hl;
    const int w = w0 + wl;

    // ---- filters -> VGPRs (pinned), reused for all planes x 4 channels ----
    float f[NF];
    #pragma unroll
    for (int k = 0; k < NF; ++k)
        f[k] = filt[k * HW + h * W + w];
    #pragma unroll
    for (int k = 0; k < NF; ++k)
        asm volatile("" : "+v"(f[k]));

    // ---- per-lane staging slots: cells lane, lane+64, lane+128, lane+192 ----
    int  coff[4];
    bool cval[4];
    #pragma unroll
    for (int k = 0; k < 4; ++k) {
        int cell = lane + 64 * k;
        int r   = cell / LW;
        int col = cell - r * LW;
        int gh  = h0 - 2 + r;
        int gw  = w0 - 2 + col;
        cval[k] = (cell < CELLS) && gh >= 0 && gh < H && gw >= 0 && gw < W;
        coff[k] = gh * W + gw;
    }
    const float* base = in + (size_t)c0 * DHW;

    float4 g[4];                      // prefetch registers (plane in flight)
    auto load_g = [&](int p) {        // issue global loads for plane p
        const bool pv = (p >= 0) && (p < D);   // block-uniform
        #pragma unroll
        for (int k = 0; k < 4; ++k) {
            float4 v = make_float4(0.f, 0.f, 0.f, 0.f);
            if (pv && cval[k]) {
                const float* pb = base + (size_t)p * HW + coff[k];
                v.x = pb[0];
                v.y = pb[DHW];
                v.z = pb[2 * DHW];
                v.w = pb[3 * DHW];
            }
            g[k] = v;
        }
    };
    auto write_g = [&](int b) {       // LDS <- prefetch regs
        #pragma unroll
        for (int k = 0; k < 4; ++k) {
            int cell = lane + 64 * k;
            if (cell < CELLS) buf[b][cell] = g[k];   // k<3 unconditional at compile time
        }
    };

    // prologue: stage plane dlo-1 into buf[0]
    load_g(dlo - 1);
    write_g(0);

    float4 a_prev = make_float4(0.f, 0.f, 0.f, 0.f);
    float4 a_cur  = a_prev;
    float* op0 = out + (size_t)c0 * DHW + h * W + w;

    for (int t = 0; t < DT + 2; ++t) {         // compute plane p = dlo-1+t
        if (t < DT + 1) load_g(dlo + t);       // prefetch next plane (in flight over compute)

        const float4* bp = &buf[t & 1][hl * LW + wl];
        float4 s0 = make_float4(0.f, 0.f, 0.f, 0.f);
        float4 s1 = s0, s2 = s0;
        #pragma unroll
        for (int i = 0; i < 5; ++i) {
            #pragma unroll
            for (int j = 0; j < 5; ++j) {
                float4 v = bp[i * LW + j];     // ds_read_b128
                float F0 = f[     i * 5 + j];
                float F1 = f[25 + i * 5 + j];
                float F2 = f[50 + i * 5 + j];
                s0.x = fmaf(F0, v.x, s0.x); s0.y = fmaf(F0, v.y, s0.y);
                s0.z = fmaf(F0, v.z, s0.z); s0.w = fmaf(F0, v.w, s0.w);
                s1.x = fmaf(F1, v.x, s1.x); s1.y = fmaf(F1, v.y, s1.y);
                s1.z = fmaf(F1, v.z, s1.z); s1.w = fmaf(F1, v.w, s1.w);
                s2.x = fmaf(F2, v.x, s2.x); s2.y = fmaf(F2, v.y, s2.y);
                s2.z = fmaf(F2, v.z, s2.z); s2.w = fmaf(F2, v.w, s2.w);
            }
        }

        if (t >= 2) {                  // out[od] complete: a_prev + s2(plane od+1)
            int od = dlo + t - 2;
            float* op = op0 + (size_t)od * HW;
            op[0]       = a_prev.x + s2.x;
            op[DHW]     = a_prev.y + s2.y;
            op[2 * DHW] = a_prev.z + s2.z;
            op[3 * DHW] = a_prev.w + s2.w;
        }
        a_prev.x = a_cur.x + s1.x; a_prev.y = a_cur.y + s1.y;
        a_prev.z = a_cur.z + s1.z; a_prev.w = a_cur.w + s1.w;
        a_cur = s0;

        if (t < DT + 1) write_g((t + 1) & 1);  // LDS write after compute; waits vmcnt on
                                               // prefetch loads that ran under the compute
    }
}

extern "C" void kernel_launch(void* const* d_in, const int* in_sizes, int n_in,
                              void* d_out, int out_size, void* d_ws, size_t ws_size,
                              hipStream_t stream)
{
    (void)in_sizes; (void)n_in; (void)out_size;
    const float* cost = (const float*)d_in[0];
    const float* filt = (const float*)d_in[1];
    float* out = (float*)d_out;

    const size_t needBytes = (size_t)C * DHW * sizeof(float);
    float* tmp = (ws_size >= needBytes) ? (float*)d_ws : (float*)d_in[0];
    // fallback writes the input buffer; harness restores d_in before every timed launch

    dim3 block(64, 1, 1);
    dim3 grid(W / TW, H / TH, (C / NC) * DS);   // 8 x 64 x 8 = 4096 blocks (1 wave each)

    lga_pass<<<grid, block, 0, stream>>>(cost, filt, out);   // pass 1: cost -> out
    lga_pass<<<grid, block, 0, stream>>>(out,  filt, tmp);   // pass 2: out  -> tmp
    lga_pass<<<grid, block, 0, stream>>>(tmp,  filt, out);   // pass 3: tmp  -> out
}

// Round 4
// 752.841 us; speedup vs baseline: 7.2438x; 7.2438x over previous
//
#include <hip/hip_runtime.h>

// LGA3D x3 (GANet local guided aggregation), fp32.
// Round 4: barrier-free wave-private tiles (no __syncthreads at all), fixed VGPR
// budget (__launch_bounds__(64,2) -> 256 cap; r3's (64,4) cap of 128 caused
// catastrophic scratch spill: VGPR=64, 3.5 GB fetch/pass).
// Channel-interleaved intermediate layout [c/4][d][h][w][4c] makes staging loads
// global_load_dwordx4 (3 per lane-plane) and output stores dwordx4.
// Pass chain: cost(canon) -> d_out(IL) -> d_in[0](IL) -> d_out(canon). No d_ws.

namespace {
constexpr int C  = 16, D = 48, H = 128, W = 256;
constexpr int NC = 4;                 // channels per LDS cell / float4
constexpr int TW = 16, TH = 4;        // per-wave output tile
constexpr int DS = 2;                 // depth split
constexpr int DT = D / DS;            // 24 output planes per block
constexpr int LH = TH + 4;            // 8 rows:  h0-2 .. h0+5
constexpr int LW = TW + 4;            // 20 cols: w0-2 .. w0+17
constexpr int CELLS = LH * LW;        // 160 cells per plane buffer
constexpr int HW = H * W;
constexpr int DHW = D * HW;
constexpr int NF = 75;
}

template<bool IN_IL, bool OUT_IL>
__global__ __launch_bounds__(64, 2)
void lga_pass(const float* __restrict__ in, const float* __restrict__ filt,
              float* __restrict__ out)
{
    __shared__ float4 buf[2][CELLS];  // 5120 B, wave-private (block = 1 wave)

    const int lane = threadIdx.x;     // 0..63
    const int hl = lane >> 4;         // 0..3
    const int wl = lane & 15;         // 0..15
    const int w0 = blockIdx.x * TW;
    const int h0 = blockIdx.y * TH;
    const int zz = blockIdx.z;
    const int cg  = zz >> 1;          // channel group 0..3
    const int dlo = (zz & 1) * DT;

    const int h = h0 + hl;
    const int w = w0 + wl;

    // ---- filters -> VGPRs (pinned), reused for all planes x 4 channels ----
    float f[NF];
    #pragma unroll
    for (int k = 0; k < NF; ++k)
        f[k] = filt[k * HW + h * W + w];
    #pragma unroll
    for (int k = 0; k < NF; ++k)
        asm volatile("" : "+v"(f[k]));

    // ---- per-lane staging slots: cells lane, lane+64, lane+128 (160 cells) ----
    int  coff[3];
    bool cval[3];
    #pragma unroll
    for (int k = 0; k < 3; ++k) {
        int cell = lane + 64 * k;
        int r   = cell / LW;
        int col = cell - r * LW;
        int gh  = h0 - 2 + r;
        int gw  = w0 - 2 + col;
        cval[k] = (cell < CELLS) && gh >= 0 && gh < H && gw >= 0 && gw < W;
        coff[k] = gh * W + gw;
    }

    const float4* in4  = (const float4*)in + (size_t)cg * DHW;        // IL input
    const float*  inc  = in + (size_t)(cg * NC) * DHW;                // canonical input

    float4 g[3];                      // prefetch registers (plane in flight)
    auto load_g = [&](int p) {
        const bool pv = (p >= 0) && (p < D);     // block-uniform
        #pragma unroll
        for (int k = 0; k < 3; ++k) {
            float4 v = make_float4(0.f, 0.f, 0.f, 0.f);
            if (pv && cval[k]) {
                if (IN_IL) {
                    v = in4[(size_t)p * HW + coff[k]];
                } else {
                    const float* pb = inc + (size_t)p * HW + coff[k];
                    v.x = pb[0];
                    v.y = pb[DHW];
                    v.z = pb[2 * DHW];
                    v.w = pb[3 * DHW];
                }
            }
            g[k] = v;
        }
    };
    auto write_g = [&](int b) {
        #pragma unroll
        for (int k = 0; k < 3; ++k) {
            int cell = lane + 64 * k;
            if (k < 2 || cell < CELLS)           // k=2: lanes 0..31 only
                buf[b][cell] = g[k];
        }
    };

    // prologue: stage plane dlo-1 into buf[0]
    load_g(dlo - 1);
    write_g(0);

    float4 a_prev = make_float4(0.f, 0.f, 0.f, 0.f);
    float4 a_cur  = a_prev;
    float4* out4 = (float4*)out + (size_t)cg * DHW + h * W + w;       // IL output
    float*  outc = out + (size_t)(cg * NC) * DHW + h * W + w;         // canonical output

    for (int t = 0; t < DT + 2; ++t) {           // compute plane p = dlo-1+t
        if (t < DT + 1) load_g(dlo + t);         // prefetch next plane

        const float4* bp = &buf[t & 1][hl * LW + wl];
        float4 s0 = make_float4(0.f, 0.f, 0.f, 0.f);
        float4 s1 = s0, s2 = s0;
        #pragma unroll
        for (int i = 0; i < 5; ++i) {
            #pragma unroll
            for (int j = 0; j < 5; ++j) {
                float4 v = bp[i * LW + j];       // ds_read_b128
                float F0 = f[     i * 5 + j];
                float F1 = f[25 + i * 5 + j];
                float F2 = f[50 + i * 5 + j];
                s0.x = fmaf(F0, v.x, s0.x); s0.y = fmaf(F0, v.y, s0.y);
                s0.z = fmaf(F0, v.z, s0.z); s0.w = fmaf(F0, v.w, s0.w);
                s1.x = fmaf(F1, v.x, s1.x); s1.y = fmaf(F1, v.y, s1.y);
                s1.z = fmaf(F1, v.z, s1.z); s1.w = fmaf(F1, v.w, s1.w);
                s2.x = fmaf(F2, v.x, s2.x); s2.y = fmaf(F2, v.y, s2.y);
                s2.z = fmaf(F2, v.z, s2.z); s2.w = fmaf(F2, v.w, s2.w);
            }
        }

        if (t >= 2) {                  // out[od] = s0(od-1) + s1(od) + s2(od+1) complete
            int od = dlo + t - 2;
            if (OUT_IL) {
                out4[(size_t)od * HW] = make_float4(a_prev.x + s2.x, a_prev.y + s2.y,
                                                    a_prev.z + s2.z, a_prev.w + s2.w);
            } else {
                float* op = outc + (size_t)od * HW;
                op[0]       = a_prev.x + s2.x;
                op[DHW]     = a_prev.y + s2.y;
                op[2 * DHW] = a_prev.z + s2.z;
                op[3 * DHW] = a_prev.w + s2.w;
            }
        }
        a_prev.x = a_cur.x + s1.x; a_prev.y = a_cur.y + s1.y;
        a_prev.z = a_cur.z + s1.z; a_prev.w = a_cur.w + s1.w;
        a_cur = s0;

        if (t < DT + 1) write_g((t + 1) & 1);    // LDS write after reads of this plane
    }
}

extern "C" void kernel_launch(void* const* d_in, const int* in_sizes, int n_in,
                              void* d_out, int out_size, void* d_ws, size_t ws_size,
                              hipStream_t stream)
{
    (void)in_sizes; (void)n_in; (void)out_size; (void)d_ws; (void)ws_size;
    const float* cost = (const float*)d_in[0];
    const float* filt = (const float*)d_in[1];
    float* out  = (float*)d_out;
    float* clob = (float*)d_in[0];   // harness restores d_in before every launch

    dim3 block(64, 1, 1);
    dim3 grid(W / TW, H / TH, (C / NC) * DS);   // 16 x 32 x 8 = 4096 blocks (1 wave each)

    // P1: cost (canonical) -> d_out (interleaved)
    lga_pass<false, true ><<<grid, block, 0, stream>>>(cost, filt, out);
    // P2: d_out (interleaved) -> d_in[0] (interleaved; input no longer needed)
    lga_pass<true,  true ><<<grid, block, 0, stream>>>(out,  filt, clob);
    // P3: d_in[0] (interleaved) -> d_out (canonical)
    lga_pass<true,  false><<<grid, block, 0, stream>>>(clob, filt, out);
}